// Round 5
// baseline (351.360 us; speedup 1.0000x reference)
//
#include <hip/hip_runtime.h>
#include <hip/hip_bf16.h>
#include <stdint.h>

#define DEVI __device__ __forceinline__

typedef __attribute__((ext_vector_type(4))) float f32x4;
typedef __attribute__((ext_vector_type(16))) float f32x16;
typedef __attribute__((ext_vector_type(8))) short bf16x8;

constexpr int nB = 2, nN = 1024, nD = 512, nH = 16, nDH = 32;

DEVI unsigned short f2bf(float x) {
  unsigned u = __float_as_uint(x);
  return (unsigned short)((u + 0x7fffu + ((u >> 16) & 1u)) >> 16);
}
DEVI float bf2f(unsigned short s) { return __uint_as_float(((unsigned)s) << 16); }
DEVI unsigned pk2(float lo, float hi_) {
  return (unsigned)f2bf(lo) | ((unsigned)f2bf(hi_) << 16);
}
DEVI float bperm(int srclane, float v) {
  return __int_as_float(__builtin_amdgcn_ds_bpermute(srclane << 2, __float_as_int(v)));
}
DEVI void gload16(const void* g, void* l) {
  __builtin_amdgcn_global_load_lds((const __attribute__((address_space(1))) void*)g,
                                   (__attribute__((address_space(3))) void*)l, 16, 0, 0);
}

// ---------------- 0. ff_w f32 -> bf16 (L2-resident weight for ffln) ---------
__global__ __launch_bounds__(256) void cvt_fw(const float* __restrict__ fw,
                                              unsigned short* __restrict__ fwb) {
  int i = blockIdx.x * 256 + threadIdx.x;  // 65536 float4s
  float4 v = reinterpret_cast<const float4*>(fw)[i];
  ushort4 o;
  o.x = f2bf(v.x); o.y = f2bf(v.y); o.z = f2bf(v.z); o.w = f2bf(v.w);
  reinterpret_cast<ushort4*>(fwb)[i] = o;
}

// ---------------- 1. QKV GEMM: fused f32->bf16 cvt + V-transpose epilogue ----
__global__ __launch_bounds__(256, 2) void qkv_gemm(const float* __restrict__ x,
                                                   const float* __restrict__ aw,
                                                   unsigned short* __restrict__ q,
                                                   unsigned short* __restrict__ kmat,
                                                   unsigned short* __restrict__ vtt) {
  __shared__ __align__(16) unsigned short sA[2][64 * 32];
  __shared__ __align__(16) unsigned short sB[2][128 * 32];
  const int tid = threadIdx.x, wid = tid >> 6, lane = tid & 63;
  const int wr = wid >> 1, wc = wid & 1;
  const long rowA = (long)blockIdx.x * 64;
  const long rowB = (long)blockIdx.y * 128;

  f32x4 acc[2][4];
#pragma unroll
  for (int mm = 0; mm < 2; ++mm)
#pragma unroll
    for (int nn = 0; nn < 4; ++nn)
#pragma unroll
      for (int r = 0; r < 4; ++r) acc[mm][nn][r] = 0.f;

  union PK { unsigned u[4]; bf16x8 v; };

  auto stage = [&](int t, int pb) {
    const int k0 = t * 32;
    {  // A = x: 64x32, 8 f32/thread -> 1 bf16x8
      const float* src = x + (rowA + (tid >> 2)) * 512 + k0 + (tid & 3) * 8;
      float4 v0 = *reinterpret_cast<const float4*>(src);
      float4 v1 = *reinterpret_cast<const float4*>(src + 4);
      PK p;
      p.u[0] = pk2(v0.x, v0.y); p.u[1] = pk2(v0.z, v0.w);
      p.u[2] = pk2(v1.x, v1.y); p.u[3] = pk2(v1.z, v1.w);
      *reinterpret_cast<bf16x8*>(&sA[pb][tid * 8]) = p.v;
    }
    {  // B = att_w: 128x32, 16 f32/thread -> 2 bf16x8
      const float* src = aw + (rowB + (tid >> 1)) * 512 + k0 + (tid & 1) * 16;
      float4 w0 = *reinterpret_cast<const float4*>(src);
      float4 w1 = *reinterpret_cast<const float4*>(src + 4);
      float4 w2 = *reinterpret_cast<const float4*>(src + 8);
      float4 w3 = *reinterpret_cast<const float4*>(src + 12);
      PK p0, p1;
      p0.u[0] = pk2(w0.x, w0.y); p0.u[1] = pk2(w0.z, w0.w);
      p0.u[2] = pk2(w1.x, w1.y); p0.u[3] = pk2(w1.z, w1.w);
      p1.u[0] = pk2(w2.x, w2.y); p1.u[1] = pk2(w2.z, w2.w);
      p1.u[2] = pk2(w3.x, w3.y); p1.u[3] = pk2(w3.z, w3.w);
      *reinterpret_cast<bf16x8*>(&sB[pb][tid * 16]) = p0.v;
      *reinterpret_cast<bf16x8*>(&sB[pb][tid * 16 + 8]) = p1.v;
    }
  };
  auto comp = [&](int pb) {
    const int kg = (lane >> 4) * 8, rlo = lane & 15;
    bf16x8 af[2], bfv[4];
#pragma unroll
    for (int mm = 0; mm < 2; ++mm)
      af[mm] = *reinterpret_cast<const bf16x8*>(&sA[pb][(32 * wr + 16 * mm + rlo) * 32 + kg]);
#pragma unroll
    for (int nn = 0; nn < 4; ++nn)
      bfv[nn] = *reinterpret_cast<const bf16x8*>(&sB[pb][(64 * wc + 16 * nn + rlo) * 32 + kg]);
#pragma unroll
    for (int mm = 0; mm < 2; ++mm)
#pragma unroll
      for (int nn = 0; nn < 4; ++nn)
        acc[mm][nn] = __builtin_amdgcn_mfma_f32_16x16x32_bf16(af[mm], bfv[nn],
                                                              acc[mm][nn], 0, 0, 0);
  };

  stage(0, 0);
  __syncthreads();
  for (int t = 0; t < 16; t += 2) {
    if (t + 1 < 16) stage(t + 1, 1);
    comp(0);
    __syncthreads();
    if (t + 2 < 16) stage(t + 2, 0);
    comp(1);
    __syncthreads();
  }

#pragma unroll
  for (int mm = 0; mm < 2; ++mm)
#pragma unroll
    for (int nn = 0; nn < 4; ++nn)
#pragma unroll
      for (int r = 0; r < 4; ++r) {
        float v = acc[mm][nn][r];
        int row = (int)rowA + 32 * wr + 16 * mm + (lane >> 4) * 4 + r;
        int col = (int)rowB + 64 * wc + 16 * nn + (lane & 15);
        int s = col >> 9, rem = col & 511;
        int h = rem >> 5, d = rem & 31;
        int b = row >> 10, n = row & 1023;
        if (s == 0) {
          q[((long)(b * nH + h) * nN + n) * nDH + d] = f2bf(v * 0.1767766952966369f);
        } else if (s == 1) {
          kmat[((long)(b * nH + h) * nN + n) * nDH + d] = f2bf(v);
        } else {
          vtt[((long)(b * nH + h) * 32 + (n >> 5)) * 1024 + d * 32 + (n & 31)] = f2bf(v);
        }
      }
}

// ---------------- 2. fused attention (flash partials over 8 j-chunks) --------
// grid: x = b*32 + it, y = jc (8-way j split). WG = 16 waves = all 16 heads.
__global__ __launch_bounds__(1024, 8) void attn_kernel(
    const unsigned short* __restrict__ qm, const unsigned short* __restrict__ km,
    const unsigned short* __restrict__ vtt,
    const float* __restrict__ pdist, const float* __restrict__ angle,
    const float* __restrict__ adj, const unsigned char* __restrict__ mask,
    const float* __restrict__ gamma_p, const float* __restrict__ gamma_adj,
    const float* __restrict__ w_bias,
    unsigned short* __restrict__ po, float* __restrict__ pm, float* __restrict__ pl) {
  const int b = blockIdx.x >> 5, it = blockIdx.x & 31;
  const int jc = blockIdx.y;
  const int tid = threadIdx.x, wid = tid >> 6, lane = tid & 63;
  const int h = wid;
  const int li = lane & 31, hi = lane >> 5;
  const int ibase = it * 32;

  __shared__ __align__(16) float s_pd[2][1024], s_adj[2][1024];
  __shared__ __align__(16) float s_a0[2][1024], s_a1[2][1024];
  __shared__ __align__(16) float s_mk[1024];

  const float gp = gamma_p[h], ga = gamma_adj[h];
  const float wb0 = w_bias[2 * h], wb1 = w_bias[2 * h + 1];

  const unsigned short* qb = qm + ((long)(b * nH + h) * nN + ibase) * nDH;
  const bf16x8 qf0 = *reinterpret_cast<const bf16x8*>(qb + li * 32 + hi * 8);
  const bf16x8 qf1 = *reinterpret_cast<const bf16x8*>(qb + li * 32 + 16 + hi * 8);

  f32x16 o;
#pragma unroll
  for (int r = 0; r < 16; ++r) o[r] = 0.f;
  float mrun = -INFINITY, lrun = 0.f;

  auto stage = [&](int s, int pb) {
    const int jbase = (jc * 4 + s) * 32;
    if (tid < 512) {  // pdist (waves 0-3) / adj (waves 4-7), XOR-swizzled
      int r = (tid >> 3) & 31, c = tid & 7;
      const float* src = (tid < 256 ? pdist : adj) +
                         ((long)b * nN + ibase + r) * nN + jbase + c * 4;
      float4 v = *reinterpret_cast<const float4*>(src);
      float* dst = (tid < 256 ? s_pd[pb] : s_adj[pb]) + r * 32 + ((c ^ (r & 7)) << 2);
      *reinterpret_cast<float4*>(dst) = v;
    } else {          // angle: de-interleave into a0/a1, same swizzle
      int t2 = tid - 512;
      int r = t2 >> 4, p = t2 & 15;
      float4 v = *reinterpret_cast<const float4*>(
          angle + (((long)b * nN + ibase + r) * nN + jbase + p * 2) * 2);
      int off = r * 32 + (((p >> 1) ^ (r & 7)) << 2) + (p & 1) * 2;
      *reinterpret_cast<float2*>(s_a0[pb] + off) = make_float2(v.x, v.z);
      *reinterpret_cast<float2*>(s_a1[pb] + off) = make_float2(v.y, v.w);
    }
  };

  auto comp = [&](int s, int pb) {
    const int jt = jc * 4 + s, jbase = jt * 32;
    const unsigned short* kb = km + ((long)(b * nH + h) * nN + jbase) * nDH;
    bf16x8 kf0 = *reinterpret_cast<const bf16x8*>(kb + li * 32 + hi * 8);
    bf16x8 kf1 = *reinterpret_cast<const bf16x8*>(kb + li * 32 + 16 + hi * 8);
    // hoist V-fragment loads: latency hides under bias+softmax VALU
    const unsigned short* vb = vtt + ((long)(b * nH + h) * 32 + jt) * 1024;
    bf16x8 vf0 = *reinterpret_cast<const bf16x8*>(vb + li * 32 + hi * 8);
    bf16x8 vf1 = *reinterpret_cast<const bf16x8*>(vb + li * 32 + 16 + hi * 8);

    f32x16 sc;
#pragma unroll
    for (int r = 0; r < 16; ++r) sc[r] = 0.f;
    sc = __builtin_amdgcn_mfma_f32_32x32x16_bf16(kf0, qf0, sc, 0, 0, 0);
    sc = __builtin_amdgcn_mfma_f32_32x32x16_bf16(kf1, qf1, sc, 0, 0, 0);

    float sv[16];
    float tmax = -INFINITY;
#pragma unroll
    for (int g = 0; g < 4; ++g) {
      const int cs = (((2 * g + hi) ^ (li & 7)) << 2);
      f32x4 pdq = *reinterpret_cast<const f32x4*>(s_pd[pb] + li * 32 + cs);
      f32x4 adq = *reinterpret_cast<const f32x4*>(s_adj[pb] + li * 32 + cs);
      f32x4 a0q = *reinterpret_cast<const f32x4*>(s_a0[pb] + li * 32 + cs);
      f32x4 a1q = *reinterpret_cast<const f32x4*>(s_a1[pb] + li * 32 + cs);
      f32x4 mkq = *reinterpret_cast<const f32x4*>(s_mk + jbase + 8 * g + 4 * hi);
#pragma unroll
      for (int u = 0; u < 4; ++u) {
        float xv = sc[4 * g + u] - gp * pdq[u] + wb0 * a0q[u] + wb1 * a1q[u]
                   + ga * adq[u] + mkq[u];
        sv[4 * g + u] = xv;
        tmax = fmaxf(tmax, xv);
      }
    }
    tmax = fmaxf(tmax, __shfl_xor(tmax, 32));
    if (__any((int)(tmax > mrun + 8.f))) {  // T13 defer-max
      float mnew = fmaxf(mrun, tmax);
      float alpha = __expf(mrun - mnew);
      lrun *= alpha;
#pragma unroll
      for (int r = 0; r < 16; ++r) o[r] *= bperm((r & 3) + 8 * (r >> 2) + 4 * hi, alpha);
      mrun = mnew;
    }
    float psum = 0.f;
#pragma unroll
    for (int r = 0; r < 16; ++r) { sv[r] = __expf(sv[r] - mrun); psum += sv[r]; }
    psum += __shfl_xor(psum, 32);
    lrun += psum;

    unsigned ow[8], rw[8];
#pragma unroll
    for (int t = 0; t < 8; ++t) ow[t] = pk2(sv[2 * t], sv[2 * t + 1]);
#pragma unroll
    for (int t = 0; t < 8; ++t) rw[t] = __shfl_xor(ow[t], 32);
    union U { unsigned u[4]; bf16x8 v; };
    U u0, u1;
    if (hi == 0) {
      u0.u[0] = ow[0]; u0.u[1] = ow[1]; u0.u[2] = rw[0]; u0.u[3] = rw[1];
      u1.u[0] = ow[4]; u1.u[1] = ow[5]; u1.u[2] = rw[4]; u1.u[3] = rw[5];
    } else {
      u0.u[0] = rw[2]; u0.u[1] = rw[3]; u0.u[2] = ow[2]; u0.u[3] = ow[3];
      u1.u[0] = rw[6]; u1.u[1] = rw[7]; u1.u[2] = ow[6]; u1.u[3] = ow[7];
    }

    o = __builtin_amdgcn_mfma_f32_32x32x16_bf16(u0.v, vf0, o, 0, 0, 0);
    o = __builtin_amdgcn_mfma_f32_32x32x16_bf16(u1.v, vf1, o, 0, 0, 0);
  };

  s_mk[tid] = mask[b * nN + tid] ? -1e9f : 0.f;
  stage(0, 0);
  __syncthreads();
  for (int s = 0; s < 4; s += 2) {
    if (s + 1 < 4) stage(s + 1, 1);
    comp(s, 0);
    __syncthreads();
    if (s + 2 < 4) stage(s + 2, 0);
    comp(s + 1, 1);
    __syncthreads();
  }

  const long task = (((long)(b * nH + h) * 32 + it) * 8 + jc);
  unsigned short* pob = po + task * 1024;
#pragma unroll
  for (int r = 0; r < 16; ++r) {
    const int irow = (r & 3) + 8 * (r >> 2) + 4 * hi;
    pob[irow * 32 + li] = f2bf(o[r]);
  }
  if (hi == 0) { pm[task * 32 + li] = mrun; pl[task * 32 + li] = lrun; }
}

// ---------------- 3. merge 8 j-chunk partials --------------------------------
__global__ __launch_bounds__(256) void merge_kernel(const unsigned short* __restrict__ po,
                                                    const float* __restrict__ pm,
                                                    const float* __restrict__ pl,
                                                    unsigned short* __restrict__ attb) {
  const int x = blockIdx.x;  // (b*16+h)*32+it
  const int t = threadIdx.x;
  const int i = t >> 3, d4 = (t & 7) * 4;
  const long tb = (long)x * 8;
  float m[8], l[8];
#pragma unroll
  for (int c = 0; c < 8; ++c) { m[c] = pm[(tb + c) * 32 + i]; l[c] = pl[(tb + c) * 32 + i]; }
  float M = m[0];
#pragma unroll
  for (int c = 1; c < 8; ++c) M = fmaxf(M, m[c]);
  float L = 0.f, w[8];
#pragma unroll
  for (int c = 0; c < 8; ++c) { w[c] = __expf(m[c] - M); L += w[c] * l[c]; }
  float o0 = 0, o1 = 0, o2 = 0, o3 = 0;
#pragma unroll
  for (int c = 0; c < 8; ++c) {
    ushort4 v = *reinterpret_cast<const ushort4*>(po + (tb + c) * 1024 + i * 32 + d4);
    o0 += w[c] * bf2f(v.x); o1 += w[c] * bf2f(v.y);
    o2 += w[c] * bf2f(v.z); o3 += w[c] * bf2f(v.w);
  }
  const float inv = 1.f / L;
  const int b = x >> 9, hh = (x >> 5) & 15, it = x & 31;
  ushort4 ov;
  ov.x = f2bf(o0 * inv); ov.y = f2bf(o1 * inv);
  ov.z = f2bf(o2 * inv); ov.w = f2bf(o3 * inv);
  *reinterpret_cast<ushort4*>(attb + ((long)b * nN + it * 32 + i) * nD + hh * 32 + d4) = ov;
}

// ---------------- 4. FF GEMM (BN=512 full row) + residual + LayerNorm -------
__global__ __launch_bounds__(512, 2) void ffln_kernel(const unsigned short* __restrict__ attb,
                                                      const unsigned short* __restrict__ fwb,
                                                      const float* __restrict__ x,
                                                      const float* __restrict__ ffb,
                                                      const float* __restrict__ lnw,
                                                      const float* __restrict__ lnb,
                                                      float* __restrict__ out) {
  __shared__ __align__(16) unsigned short sA[2][32 * 32];
  __shared__ __align__(16) unsigned short sB[2][512 * 32];
  __shared__ float rs_[32][4], rs2_[32][4];
  const int tid = threadIdx.x, wid = tid >> 6, lane = tid & 63;
  const int wr = wid >> 2, wc = wid & 3;
  const long rowA = (long)blockIdx.x * 32;

  f32x4 acc[8];
#pragma unroll
  for (int nn = 0; nn < 8; ++nn)
#pragma unroll
    for (int r = 0; r < 4; ++r) acc[nn][r] = 0.f;

  auto stage = [&](int t, int pb) {
    const int k0 = t * 32;
    if (tid < 128)  // A = attb (bf16): 32x32 via global_load_lds
      gload16(&attb[(rowA + (tid >> 2)) * 512 + k0 + (tid & 3) * 8], &sA[pb][tid * 8]);
    // B = fwb (bf16): 512x32 via global_load_lds, 4 chunks/thread
#pragma unroll
    for (int c = 0; c < 4; ++c) {
      int off = (tid + 512 * c) * 8;
      int r = off >> 5, s8 = off & 31;
      gload16(&fwb[(long)r * 512 + k0 + s8], &sB[pb][off]);
    }
  };
  auto comp = [&](int pb) {
    const int kg = (lane >> 4) * 8, rlo = lane & 15;
    bf16x8 af = *reinterpret_cast<const bf16x8*>(&sA[pb][(16 * wr + rlo) * 32 + kg]);
#pragma unroll
    for (int nn = 0; nn < 8; ++nn) {
      bf16x8 bfv = *reinterpret_cast<const bf16x8*>(&sB[pb][(128 * wc + 16 * nn + rlo) * 32 + kg]);
      acc[nn] = __builtin_amdgcn_mfma_f32_16x16x32_bf16(af, bfv, acc[nn], 0, 0, 0);
    }
  };

  stage(0, 0);
  __syncthreads();
  for (int t = 0; t < 16; t += 2) {
    if (t + 1 < 16) stage(t + 1, 1);
    comp(0);
    __syncthreads();
    if (t + 2 < 16) stage(t + 2, 0);
    comp(1);
    __syncthreads();
  }

  // ---- epilogue: y = x + ff_out + ffb; LN over the row ----
  float colf[8], colw[8], colb[8];
#pragma unroll
  for (int nn = 0; nn < 8; ++nn) {
    int c = 128 * wc + 16 * nn + (lane & 15);
    colf[nn] = ffb[c]; colw[nn] = lnw[c]; colb[nn] = lnb[c];
  }
  float s[4], s2[4];
#pragma unroll
  for (int r = 0; r < 4; ++r) { s[r] = 0.f; s2[r] = 0.f; }
#pragma unroll
  for (int nn = 0; nn < 8; ++nn)
#pragma unroll
    for (int r = 0; r < 4; ++r) {
      long row = rowA + 16 * wr + 4 * (lane >> 4) + r;
      int c = 128 * wc + 16 * nn + (lane & 15);
      float y = acc[nn][r] + colf[nn] + x[row * 512 + c];
      acc[nn][r] = y;
      s[r] += y; s2[r] += y * y;
    }
#pragma unroll
  for (int off = 1; off < 16; off <<= 1)
#pragma unroll
    for (int r = 0; r < 4; ++r) {
      s[r] += __shfl_xor(s[r], off);
      s2[r] += __shfl_xor(s2[r], off);
    }
  if ((lane & 15) == 0) {
#pragma unroll
    for (int r = 0; r < 4; ++r) {
      int rowl = 16 * wr + 4 * (lane >> 4) + r;
      rs_[rowl][wc] = s[r];
      rs2_[rowl][wc] = s2[r];
    }
  }
  __syncthreads();
#pragma unroll
  for (int r = 0; r < 4; ++r) {
    int rowl = 16 * wr + 4 * (lane >> 4) + r;
    float S = rs_[rowl][0] + rs_[rowl][1] + rs_[rowl][2] + rs_[rowl][3];
    float S2 = rs2_[rowl][0] + rs2_[rowl][1] + rs2_[rowl][2] + rs2_[rowl][3];
    float mu = S * (1.f / 512.f);
    float var = S2 * (1.f / 512.f) - mu * mu;
    float rstd = rsqrtf(var + 1e-5f);
    long row = rowA + rowl;
#pragma unroll
    for (int nn = 0; nn < 8; ++nn) {
      int c = 128 * wc + 16 * nn + (lane & 15);
      out[row * 512 + c] = (acc[nn][r] - mu) * rstd * colw[nn] + colb[nn];
    }
  }
}

// ---------------- launch -----------------------------------------------------
extern "C" void kernel_launch(void* const* d_in, const int* in_sizes, int n_in,
                              void* d_out, int out_size, void* d_ws, size_t ws_size,
                              hipStream_t stream) {
  const float* x         = (const float*)d_in[0];
  const float* pdist     = (const float*)d_in[1];
  const float* angle     = (const float*)d_in[2];
  const float* adj       = (const float*)d_in[3];
  const unsigned char* mask = (const unsigned char*)d_in[4];
  const float* gamma_p   = (const float*)d_in[5];
  const float* gamma_adj = (const float*)d_in[6];
  const float* w_bias    = (const float*)d_in[7];
  const float* att_w     = (const float*)d_in[8];
  const float* ff_w      = (const float*)d_in[9];
  const float* ff_b      = (const float*)d_in[10];
  const float* ln_w      = (const float*)d_in[11];
  const float* ln_b      = (const float*)d_in[12];
  float* out = (float*)d_out;

  char* ws = (char*)d_ws;
  unsigned short* qm   = (unsigned short*)(ws);               // 2 MB
  unsigned short* km   = (unsigned short*)(ws + 0x200000);    // 2 MB
  unsigned short* vtt  = (unsigned short*)(ws + 0x400000);    // 2 MB
  unsigned short* po   = (unsigned short*)(ws + 0x600000);    // 16 MB
  float*          pm   = (float*)(ws + 0x1600000);            // 1 MB
  float*          pl   = (float*)(ws + 0x1700000);            // 1 MB
  unsigned short* attb = (unsigned short*)(ws + 0x1800000);   // 2 MB
  unsigned short* fwb  = (unsigned short*)(ws + 0x1A00000);   // 0.5 MB

  hipLaunchKernelGGL(cvt_fw, dim3(256), dim3(256), 0, stream, ff_w, fwb);
  hipLaunchKernelGGL(qkv_gemm, dim3(32, 12), dim3(256), 0, stream,
                     x, att_w, qm, km, vtt);
  hipLaunchKernelGGL(attn_kernel, dim3(64, 8), dim3(1024), 0, stream,
                     qm, km, vtt, pdist, angle, adj, mask,
                     gamma_p, gamma_adj, w_bias, po, pm, pl);
  hipLaunchKernelGGL(merge_kernel, dim3(1024), dim3(256), 0, stream,
                     po, pm, pl, attb);
  hipLaunchKernelGGL(ffln_kernel, dim3(64), dim3(512), 0, stream,
                     attb, fwb, x, ff_b, ln_w, ln_b, out);
}

// Round 6
// 181.658 us; speedup vs baseline: 1.9342x; 1.9342x over previous
//
#include <hip/hip_runtime.h>
#include <hip/hip_bf16.h>
#include <stdint.h>

#define DEVI __device__ __forceinline__

typedef __attribute__((ext_vector_type(4))) float f32x4;
typedef __attribute__((ext_vector_type(16))) float f32x16;
typedef __attribute__((ext_vector_type(8))) short bf16x8;

constexpr int nB = 2, nN = 1024, nD = 512, nH = 16, nDH = 32;

DEVI unsigned short f2bf(float x) {
  unsigned u = __float_as_uint(x);
  return (unsigned short)((u + 0x7fffu + ((u >> 16) & 1u)) >> 16);
}
DEVI float bf2f(unsigned short s) { return __uint_as_float(((unsigned)s) << 16); }
DEVI unsigned pk2(float lo, float hi_) {
  return (unsigned)f2bf(lo) | ((unsigned)f2bf(hi_) << 16);
}
DEVI float bperm(int srclane, float v) {
  return __int_as_float(__builtin_amdgcn_ds_bpermute(srclane << 2, __float_as_int(v)));
}
DEVI void gload16(const void* g, void* l) {
  __builtin_amdgcn_global_load_lds((const __attribute__((address_space(1))) void*)g,
                                   (__attribute__((address_space(3))) void*)l, 16, 0, 0);
}

// ---------------- 0. ff_w f32 -> bf16 (L2-resident weight for ffln) ---------
__global__ __launch_bounds__(256) void cvt_fw(const float* __restrict__ fw,
                                              unsigned short* __restrict__ fwb) {
  int i = blockIdx.x * 256 + threadIdx.x;  // 65536 float4s
  float4 v = reinterpret_cast<const float4*>(fw)[i];
  ushort4 o;
  o.x = f2bf(v.x); o.y = f2bf(v.y); o.z = f2bf(v.z); o.w = f2bf(v.w);
  reinterpret_cast<ushort4*>(fwb)[i] = o;
}

// ---------------- 1. QKV GEMM: fused f32->bf16 cvt + V-transpose epilogue ----
__global__ __launch_bounds__(256, 2) void qkv_gemm(const float* __restrict__ x,
                                                   const float* __restrict__ aw,
                                                   unsigned short* __restrict__ q,
                                                   unsigned short* __restrict__ kmat,
                                                   unsigned short* __restrict__ vtt) {
  __shared__ __align__(16) unsigned short sA[2][64 * 32];
  __shared__ __align__(16) unsigned short sB[2][128 * 32];
  const int tid = threadIdx.x, wid = tid >> 6, lane = tid & 63;
  const int wr = wid >> 1, wc = wid & 1;
  const long rowA = (long)blockIdx.x * 64;
  const long rowB = (long)blockIdx.y * 128;

  f32x4 acc[2][4];
#pragma unroll
  for (int mm = 0; mm < 2; ++mm)
#pragma unroll
    for (int nn = 0; nn < 4; ++nn)
#pragma unroll
      for (int r = 0; r < 4; ++r) acc[mm][nn][r] = 0.f;

  union PK { unsigned u[4]; bf16x8 v; };

  auto stage = [&](int t, int pb) {
    const int k0 = t * 32;
    {  // A = x: 64x32, 8 f32/thread -> 1 bf16x8
      const float* src = x + (rowA + (tid >> 2)) * 512 + k0 + (tid & 3) * 8;
      float4 v0 = *reinterpret_cast<const float4*>(src);
      float4 v1 = *reinterpret_cast<const float4*>(src + 4);
      PK p;
      p.u[0] = pk2(v0.x, v0.y); p.u[1] = pk2(v0.z, v0.w);
      p.u[2] = pk2(v1.x, v1.y); p.u[3] = pk2(v1.z, v1.w);
      *reinterpret_cast<bf16x8*>(&sA[pb][tid * 8]) = p.v;
    }
    {  // B = att_w: 128x32, 16 f32/thread -> 2 bf16x8
      const float* src = aw + (rowB + (tid >> 1)) * 512 + k0 + (tid & 1) * 16;
      float4 w0 = *reinterpret_cast<const float4*>(src);
      float4 w1 = *reinterpret_cast<const float4*>(src + 4);
      float4 w2 = *reinterpret_cast<const float4*>(src + 8);
      float4 w3 = *reinterpret_cast<const float4*>(src + 12);
      PK p0, p1;
      p0.u[0] = pk2(w0.x, w0.y); p0.u[1] = pk2(w0.z, w0.w);
      p0.u[2] = pk2(w1.x, w1.y); p0.u[3] = pk2(w1.z, w1.w);
      p1.u[0] = pk2(w2.x, w2.y); p1.u[1] = pk2(w2.z, w2.w);
      p1.u[2] = pk2(w3.x, w3.y); p1.u[3] = pk2(w3.z, w3.w);
      *reinterpret_cast<bf16x8*>(&sB[pb][tid * 16]) = p0.v;
      *reinterpret_cast<bf16x8*>(&sB[pb][tid * 16 + 8]) = p1.v;
    }
  };
  auto comp = [&](int pb) {
    const int kg = (lane >> 4) * 8, rlo = lane & 15;
    bf16x8 af[2], bfv[4];
#pragma unroll
    for (int mm = 0; mm < 2; ++mm)
      af[mm] = *reinterpret_cast<const bf16x8*>(&sA[pb][(32 * wr + 16 * mm + rlo) * 32 + kg]);
#pragma unroll
    for (int nn = 0; nn < 4; ++nn)
      bfv[nn] = *reinterpret_cast<const bf16x8*>(&sB[pb][(64 * wc + 16 * nn + rlo) * 32 + kg]);
#pragma unroll
    for (int mm = 0; mm < 2; ++mm)
#pragma unroll
      for (int nn = 0; nn < 4; ++nn)
        acc[mm][nn] = __builtin_amdgcn_mfma_f32_16x16x32_bf16(af[mm], bfv[nn],
                                                              acc[mm][nn], 0, 0, 0);
  };

  stage(0, 0);
  __syncthreads();
  for (int t = 0; t < 16; t += 2) {
    if (t + 1 < 16) stage(t + 1, 1);
    comp(0);
    __syncthreads();
    if (t + 2 < 16) stage(t + 2, 0);
    comp(1);
    __syncthreads();
  }

#pragma unroll
  for (int mm = 0; mm < 2; ++mm)
#pragma unroll
    for (int nn = 0; nn < 4; ++nn)
#pragma unroll
      for (int r = 0; r < 4; ++r) {
        float v = acc[mm][nn][r];
        int row = (int)rowA + 32 * wr + 16 * mm + (lane >> 4) * 4 + r;
        int col = (int)rowB + 64 * wc + 16 * nn + (lane & 15);
        int s = col >> 9, rem = col & 511;
        int h = rem >> 5, d = rem & 31;
        int b = row >> 10, n = row & 1023;
        if (s == 0) {
          q[((long)(b * nH + h) * nN + n) * nDH + d] = f2bf(v * 0.1767766952966369f);
        } else if (s == 1) {
          kmat[((long)(b * nH + h) * nN + n) * nDH + d] = f2bf(v);
        } else {
          vtt[((long)(b * nH + h) * 32 + (n >> 5)) * 1024 + d * 32 + (n & 31)] = f2bf(v);
        }
      }
}

// ---------------- 2. fused attention (flash partials over 8 j-chunks) --------
// grid: x = b*32 + it, y = jc (8-way j split). WG = 16 waves = all 16 heads.
// launch_bounds (1024,4): r4 showed this compiles to VGPR=64, zero spill.
// (1024,8) forced VGPR=32 -> 460 MB scratch spill traffic, 3x slowdown (r5).
__global__ __launch_bounds__(1024, 4) void attn_kernel(
    const unsigned short* __restrict__ qm, const unsigned short* __restrict__ km,
    const unsigned short* __restrict__ vtt,
    const float* __restrict__ pdist, const float* __restrict__ angle,
    const float* __restrict__ adj, const unsigned char* __restrict__ mask,
    const float* __restrict__ gamma_p, const float* __restrict__ gamma_adj,
    const float* __restrict__ w_bias,
    unsigned short* __restrict__ po, float* __restrict__ pm, float* __restrict__ pl) {
  const int b = blockIdx.x >> 5, it = blockIdx.x & 31;
  const int jc = blockIdx.y;
  const int tid = threadIdx.x, wid = tid >> 6, lane = tid & 63;
  const int h = wid;
  const int li = lane & 31, hi = lane >> 5;
  const int ibase = it * 32;

  __shared__ __align__(16) float s_pd[2][1024], s_adj[2][1024];
  __shared__ __align__(16) float s_a0[2][1024], s_a1[2][1024];
  __shared__ __align__(16) float s_mk[1024];

  const float gp = gamma_p[h], ga = gamma_adj[h];
  const float wb0 = w_bias[2 * h], wb1 = w_bias[2 * h + 1];

  const unsigned short* qb = qm + ((long)(b * nH + h) * nN + ibase) * nDH;
  const bf16x8 qf0 = *reinterpret_cast<const bf16x8*>(qb + li * 32 + hi * 8);
  const bf16x8 qf1 = *reinterpret_cast<const bf16x8*>(qb + li * 32 + 16 + hi * 8);

  f32x16 o;
#pragma unroll
  for (int r = 0; r < 16; ++r) o[r] = 0.f;
  float mrun = -INFINITY, lrun = 0.f;

  auto stage = [&](int s, int pb) {
    const int jbase = (jc * 4 + s) * 32;
    if (tid < 512) {  // pdist (waves 0-3) / adj (waves 4-7), XOR-swizzled
      int r = (tid >> 3) & 31, c = tid & 7;
      const float* src = (tid < 256 ? pdist : adj) +
                         ((long)b * nN + ibase + r) * nN + jbase + c * 4;
      float4 v = *reinterpret_cast<const float4*>(src);
      float* dst = (tid < 256 ? s_pd[pb] : s_adj[pb]) + r * 32 + ((c ^ (r & 7)) << 2);
      *reinterpret_cast<float4*>(dst) = v;
    } else {          // angle: de-interleave into a0/a1, same swizzle
      int t2 = tid - 512;
      int r = t2 >> 4, p = t2 & 15;
      float4 v = *reinterpret_cast<const float4*>(
          angle + (((long)b * nN + ibase + r) * nN + jbase + p * 2) * 2);
      int off = r * 32 + (((p >> 1) ^ (r & 7)) << 2) + (p & 1) * 2;
      *reinterpret_cast<float2*>(s_a0[pb] + off) = make_float2(v.x, v.z);
      *reinterpret_cast<float2*>(s_a1[pb] + off) = make_float2(v.y, v.w);
    }
  };

  auto comp = [&](int s, int pb) {
    const int jt = jc * 4 + s, jbase = jt * 32;
    const unsigned short* kb = km + ((long)(b * nH + h) * nN + jbase) * nDH;
    bf16x8 kf0 = *reinterpret_cast<const bf16x8*>(kb + li * 32 + hi * 8);
    bf16x8 kf1 = *reinterpret_cast<const bf16x8*>(kb + li * 32 + 16 + hi * 8);
    // hoist V-fragment loads: latency hides under bias+softmax VALU
    const unsigned short* vb = vtt + ((long)(b * nH + h) * 32 + jt) * 1024;
    bf16x8 vf0 = *reinterpret_cast<const bf16x8*>(vb + li * 32 + hi * 8);
    bf16x8 vf1 = *reinterpret_cast<const bf16x8*>(vb + li * 32 + 16 + hi * 8);

    f32x16 sc;
#pragma unroll
    for (int r = 0; r < 16; ++r) sc[r] = 0.f;
    sc = __builtin_amdgcn_mfma_f32_32x32x16_bf16(kf0, qf0, sc, 0, 0, 0);
    sc = __builtin_amdgcn_mfma_f32_32x32x16_bf16(kf1, qf1, sc, 0, 0, 0);

    float sv[16];
    float tmax = -INFINITY;
#pragma unroll
    for (int g = 0; g < 4; ++g) {
      const int cs = (((2 * g + hi) ^ (li & 7)) << 2);
      f32x4 pdq = *reinterpret_cast<const f32x4*>(s_pd[pb] + li * 32 + cs);
      f32x4 adq = *reinterpret_cast<const f32x4*>(s_adj[pb] + li * 32 + cs);
      f32x4 a0q = *reinterpret_cast<const f32x4*>(s_a0[pb] + li * 32 + cs);
      f32x4 a1q = *reinterpret_cast<const f32x4*>(s_a1[pb] + li * 32 + cs);
      f32x4 mkq = *reinterpret_cast<const f32x4*>(s_mk + jbase + 8 * g + 4 * hi);
#pragma unroll
      for (int u = 0; u < 4; ++u) {
        float xv = sc[4 * g + u] - gp * pdq[u] + wb0 * a0q[u] + wb1 * a1q[u]
                   + ga * adq[u] + mkq[u];
        sv[4 * g + u] = xv;
        tmax = fmaxf(tmax, xv);
      }
    }
    tmax = fmaxf(tmax, __shfl_xor(tmax, 32));
    if (__any((int)(tmax > mrun + 8.f))) {  // T13 defer-max
      float mnew = fmaxf(mrun, tmax);
      float alpha = __expf(mrun - mnew);
      lrun *= alpha;
#pragma unroll
      for (int r = 0; r < 16; ++r) o[r] *= bperm((r & 3) + 8 * (r >> 2) + 4 * hi, alpha);
      mrun = mnew;
    }
    float psum = 0.f;
#pragma unroll
    for (int r = 0; r < 16; ++r) { sv[r] = __expf(sv[r] - mrun); psum += sv[r]; }
    psum += __shfl_xor(psum, 32);
    lrun += psum;

    unsigned ow[8], rw[8];
#pragma unroll
    for (int t = 0; t < 8; ++t) ow[t] = pk2(sv[2 * t], sv[2 * t + 1]);
#pragma unroll
    for (int t = 0; t < 8; ++t) rw[t] = __shfl_xor(ow[t], 32);
    union U { unsigned u[4]; bf16x8 v; };
    U u0, u1;
    if (hi == 0) {
      u0.u[0] = ow[0]; u0.u[1] = ow[1]; u0.u[2] = rw[0]; u0.u[3] = rw[1];
      u1.u[0] = ow[4]; u1.u[1] = ow[5]; u1.u[2] = rw[4]; u1.u[3] = rw[5];
    } else {
      u0.u[0] = rw[2]; u0.u[1] = rw[3]; u0.u[2] = ow[2]; u0.u[3] = ow[3];
      u1.u[0] = rw[6]; u1.u[1] = rw[7]; u1.u[2] = ow[6]; u1.u[3] = ow[7];
    }

    o = __builtin_amdgcn_mfma_f32_32x32x16_bf16(u0.v, vf0, o, 0, 0, 0);
    o = __builtin_amdgcn_mfma_f32_32x32x16_bf16(u1.v, vf1, o, 0, 0, 0);
  };

  s_mk[tid] = mask[b * nN + tid] ? -1e9f : 0.f;
  stage(0, 0);
  __syncthreads();
  for (int s = 0; s < 4; s += 2) {
    if (s + 1 < 4) stage(s + 1, 1);
    comp(s, 0);
    __syncthreads();
    if (s + 2 < 4) stage(s + 2, 0);
    comp(s + 1, 1);
    __syncthreads();
  }

  const long task = (((long)(b * nH + h) * 32 + it) * 8 + jc);
  unsigned short* pob = po + task * 1024;
#pragma unroll
  for (int r = 0; r < 16; ++r) {
    const int irow = (r & 3) + 8 * (r >> 2) + 4 * hi;
    pob[irow * 32 + li] = f2bf(o[r]);
  }
  if (hi == 0) { pm[task * 32 + li] = mrun; pl[task * 32 + li] = lrun; }
}

// ---------------- 3. merge 8 j-chunk partials --------------------------------
__global__ __launch_bounds__(256) void merge_kernel(const unsigned short* __restrict__ po,
                                                    const float* __restrict__ pm,
                                                    const float* __restrict__ pl,
                                                    unsigned short* __restrict__ attb) {
  const int x = blockIdx.x;  // (b*16+h)*32+it
  const int t = threadIdx.x;
  const int i = t >> 3, d4 = (t & 7) * 4;
  const long tb = (long)x * 8;
  float m[8], l[8];
#pragma unroll
  for (int c = 0; c < 8; ++c) { m[c] = pm[(tb + c) * 32 + i]; l[c] = pl[(tb + c) * 32 + i]; }
  float M = m[0];
#pragma unroll
  for (int c = 1; c < 8; ++c) M = fmaxf(M, m[c]);
  float L = 0.f, w[8];
#pragma unroll
  for (int c = 0; c < 8; ++c) { w[c] = __expf(m[c] - M); L += w[c] * l[c]; }
  float o0 = 0, o1 = 0, o2 = 0, o3 = 0;
#pragma unroll
  for (int c = 0; c < 8; ++c) {
    ushort4 v = *reinterpret_cast<const ushort4*>(po + (tb + c) * 1024 + i * 32 + d4);
    o0 += w[c] * bf2f(v.x); o1 += w[c] * bf2f(v.y);
    o2 += w[c] * bf2f(v.z); o3 += w[c] * bf2f(v.w);
  }
  const float inv = 1.f / L;
  const int b = x >> 9, hh = (x >> 5) & 15, it = x & 31;
  ushort4 ov;
  ov.x = f2bf(o0 * inv); ov.y = f2bf(o1 * inv);
  ov.z = f2bf(o2 * inv); ov.w = f2bf(o3 * inv);
  *reinterpret_cast<ushort4*>(attb + ((long)b * nN + it * 32 + i) * nD + hh * 32 + d4) = ov;
}

// ---------------- 4. FF GEMM (BN=512 full row) + residual + LayerNorm -------
__global__ __launch_bounds__(512, 2) void ffln_kernel(const unsigned short* __restrict__ attb,
                                                      const unsigned short* __restrict__ fwb,
                                                      const float* __restrict__ x,
                                                      const float* __restrict__ ffb,
                                                      const float* __restrict__ lnw,
                                                      const float* __restrict__ lnb,
                                                      float* __restrict__ out) {
  __shared__ __align__(16) unsigned short sA[2][32 * 32];
  __shared__ __align__(16) unsigned short sB[2][512 * 32];
  __shared__ float rs_[32][4], rs2_[32][4];
  const int tid = threadIdx.x, wid = tid >> 6, lane = tid & 63;
  const int wr = wid >> 2, wc = wid & 3;
  const long rowA = (long)blockIdx.x * 32;

  f32x4 acc[8];
#pragma unroll
  for (int nn = 0; nn < 8; ++nn)
#pragma unroll
    for (int r = 0; r < 4; ++r) acc[nn][r] = 0.f;

  auto stage = [&](int t, int pb) {
    const int k0 = t * 32;
    if (tid < 128)  // A = attb (bf16): 32x32 via global_load_lds
      gload16(&attb[(rowA + (tid >> 2)) * 512 + k0 + (tid & 3) * 8], &sA[pb][tid * 8]);
    // B = fwb (bf16): 512x32 via global_load_lds, 4 chunks/thread
#pragma unroll
    for (int c = 0; c < 4; ++c) {
      int off = (tid + 512 * c) * 8;
      int r = off >> 5, s8 = off & 31;
      gload16(&fwb[(long)r * 512 + k0 + s8], &sB[pb][off]);
    }
  };
  auto comp = [&](int pb) {
    const int kg = (lane >> 4) * 8, rlo = lane & 15;
    bf16x8 af = *reinterpret_cast<const bf16x8*>(&sA[pb][(16 * wr + rlo) * 32 + kg]);
#pragma unroll
    for (int nn = 0; nn < 8; ++nn) {
      bf16x8 bfv = *reinterpret_cast<const bf16x8*>(&sB[pb][(128 * wc + 16 * nn + rlo) * 32 + kg]);
      acc[nn] = __builtin_amdgcn_mfma_f32_16x16x32_bf16(af, bfv, acc[nn], 0, 0, 0);
    }
  };

  stage(0, 0);
  __syncthreads();
  for (int t = 0; t < 16; t += 2) {
    if (t + 1 < 16) stage(t + 1, 1);
    comp(0);
    __syncthreads();
    if (t + 2 < 16) stage(t + 2, 0);
    comp(1);
    __syncthreads();
  }

  // ---- epilogue: y = x + ff_out + ffb; LN over the row ----
  float colf[8], colw[8], colb[8];
#pragma unroll
  for (int nn = 0; nn < 8; ++nn) {
    int c = 128 * wc + 16 * nn + (lane & 15);
    colf[nn] = ffb[c]; colw[nn] = lnw[c]; colb[nn] = lnb[c];
  }
  float s[4], s2[4];
#pragma unroll
  for (int r = 0; r < 4; ++r) { s[r] = 0.f; s2[r] = 0.f; }
#pragma unroll
  for (int nn = 0; nn < 8; ++nn)
#pragma unroll
    for (int r = 0; r < 4; ++r) {
      long row = rowA + 16 * wr + 4 * (lane >> 4) + r;
      int c = 128 * wc + 16 * nn + (lane & 15);
      float y = acc[nn][r] + colf[nn] + x[row * 512 + c];
      acc[nn][r] = y;
      s[r] += y; s2[r] += y * y;
    }
#pragma unroll
  for (int off = 1; off < 16; off <<= 1)
#pragma unroll
    for (int r = 0; r < 4; ++r) {
      s[r] += __shfl_xor(s[r], off);
      s2[r] += __shfl_xor(s2[r], off);
    }
  if ((lane & 15) == 0) {
#pragma unroll
    for (int r = 0; r < 4; ++r) {
      int rowl = 16 * wr + 4 * (lane >> 4) + r;
      rs_[rowl][wc] = s[r];
      rs2_[rowl][wc] = s2[r];
    }
  }
  __syncthreads();
#pragma unroll
  for (int r = 0; r < 4; ++r) {
    int rowl = 16 * wr + 4 * (lane >> 4) + r;
    float S = rs_[rowl][0] + rs_[rowl][1] + rs_[rowl][2] + rs_[rowl][3];
    float S2 = rs2_[rowl][0] + rs2_[rowl][1] + rs2_[rowl][2] + rs2_[rowl][3];
    float mu = S * (1.f / 512.f);
    float var = S2 * (1.f / 512.f) - mu * mu;
    float rstd = rsqrtf(var + 1e-5f);
    long row = rowA + rowl;
#pragma unroll
    for (int nn = 0; nn < 8; ++nn) {
      int c = 128 * wc + 16 * nn + (lane & 15);
      out[row * 512 + c] = (acc[nn][r] - mu) * rstd * colw[nn] + colb[nn];
    }
  }
}

// ---------------- launch -----------------------------------------------------
extern "C" void kernel_launch(void* const* d_in, const int* in_sizes, int n_in,
                              void* d_out, int out_size, void* d_ws, size_t ws_size,
                              hipStream_t stream) {
  const float* x         = (const float*)d_in[0];
  const float* pdist     = (const float*)d_in[1];
  const float* angle     = (const float*)d_in[2];
  const float* adj       = (const float*)d_in[3];
  const unsigned char* mask = (const unsigned char*)d_in[4];
  const float* gamma_p   = (const float*)d_in[5];
  const float* gamma_adj = (const float*)d_in[6];
  const float* w_bias    = (const float*)d_in[7];
  const float* att_w     = (const float*)d_in[8];
  const float* ff_w      = (const float*)d_in[9];
  const float* ff_b      = (const float*)d_in[10];
  const float* ln_w      = (const float*)d_in[11];
  const float* ln_b      = (const float*)d_in[12];
  float* out = (float*)d_out;

  char* ws = (char*)d_ws;
  unsigned short* qm   = (unsigned short*)(ws);               // 2 MB
  unsigned short* km   = (unsigned short*)(ws + 0x200000);    // 2 MB
  unsigned short* vtt  = (unsigned short*)(ws + 0x400000);    // 2 MB
  unsigned short* po   = (unsigned short*)(ws + 0x600000);    // 16 MB
  float*          pm   = (float*)(ws + 0x1600000);            // 1 MB
  float*          pl   = (float*)(ws + 0x1700000);            // 1 MB
  unsigned short* attb = (unsigned short*)(ws + 0x1800000);   // 2 MB
  unsigned short* fwb  = (unsigned short*)(ws + 0x1A00000);   // 0.5 MB

  hipLaunchKernelGGL(cvt_fw, dim3(256), dim3(256), 0, stream, ff_w, fwb);
  hipLaunchKernelGGL(qkv_gemm, dim3(32, 12), dim3(256), 0, stream,
                     x, att_w, qm, km, vtt);
  hipLaunchKernelGGL(attn_kernel, dim3(64, 8), dim3(1024), 0, stream,
                     qm, km, vtt, pdist, angle, adj, mask,
                     gamma_p, gamma_adj, w_bias, po, pm, pl);
  hipLaunchKernelGGL(merge_kernel, dim3(1024), dim3(256), 0, stream,
                     po, pm, pl, attb);
  hipLaunchKernelGGL(ffln_kernel, dim3(64), dim3(512), 0, stream,
                     attb, fwb, x, ff_b, ln_w, ln_b, out);
}

// Round 7
// 178.052 us; speedup vs baseline: 1.9734x; 1.0203x over previous
//
#include <hip/hip_runtime.h>
#include <hip/hip_bf16.h>
#include <stdint.h>

#define DEVI __device__ __forceinline__

typedef __attribute__((ext_vector_type(4))) float f32x4;
typedef __attribute__((ext_vector_type(16))) float f32x16;
typedef __attribute__((ext_vector_type(8))) short bf16x8;

constexpr int nB = 2, nN = 1024, nD = 512, nH = 16, nDH = 32;
constexpr float L2E = 1.4426950408889634f;

DEVI unsigned short f2bf(float x) {
  unsigned u = __float_as_uint(x);
  return (unsigned short)((u + 0x7fffu + ((u >> 16) & 1u)) >> 16);
}
DEVI float bf2f(unsigned short s) { return __uint_as_float(((unsigned)s) << 16); }
DEVI unsigned pkcvt(float lo, float hi_) {  // v_cvt_pk_bf16_f32
  __hip_bfloat162 h = __float22bfloat162_rn(make_float2(lo, hi_));
  union { __hip_bfloat162 h; unsigned u; } c; c.h = h; return c.u;
}
DEVI float bperm(int srclane, float v) {
  return __int_as_float(__builtin_amdgcn_ds_bpermute(srclane << 2, __float_as_int(v)));
}
DEVI void gload16(const void* g, void* l) {
  __builtin_amdgcn_global_load_lds((const __attribute__((address_space(1))) void*)g,
                                   (__attribute__((address_space(3))) void*)l, 16, 0, 0);
}

// ---------------- 0. ff_w f32 -> bf16 ----------------------------------------
__global__ __launch_bounds__(256) void cvt_fw(const float* __restrict__ fw,
                                              unsigned short* __restrict__ fwb) {
  int i = blockIdx.x * 256 + threadIdx.x;  // 65536 float4s
  float4 v = reinterpret_cast<const float4*>(fw)[i];
  uint2 p;
  p.x = pkcvt(v.x, v.y); p.y = pkcvt(v.z, v.w);
  reinterpret_cast<uint2*>(fwb)[i] = p;
}

// ---------------- 1. QKV GEMM: fused cvt + V-transpose epilogue --------------
// q scaled by (1/sqrt(32))*log2(e)  -> scores come out in log2 domain.
__global__ __launch_bounds__(256, 2) void qkv_gemm(const float* __restrict__ x,
                                                   const float* __restrict__ aw,
                                                   unsigned short* __restrict__ q,
                                                   unsigned short* __restrict__ kmat,
                                                   unsigned short* __restrict__ vtt) {
  __shared__ __align__(16) unsigned short sA[2][64 * 32];
  __shared__ __align__(16) unsigned short sB[2][128 * 32];
  const int tid = threadIdx.x, wid = tid >> 6, lane = tid & 63;
  const int wr = wid >> 1, wc = wid & 1;
  const long rowA = (long)blockIdx.x * 64;
  const long rowB = (long)blockIdx.y * 128;

  f32x4 acc[2][4];
#pragma unroll
  for (int mm = 0; mm < 2; ++mm)
#pragma unroll
    for (int nn = 0; nn < 4; ++nn)
#pragma unroll
      for (int r = 0; r < 4; ++r) acc[mm][nn][r] = 0.f;

  union PK { unsigned u[4]; bf16x8 v; };

  auto stage = [&](int t, int pb) {
    const int k0 = t * 32;
    {  // A = x: 64x32, 8 f32/thread -> 1 bf16x8
      const float* src = x + (rowA + (tid >> 2)) * 512 + k0 + (tid & 3) * 8;
      float4 v0 = *reinterpret_cast<const float4*>(src);
      float4 v1 = *reinterpret_cast<const float4*>(src + 4);
      PK p;
      p.u[0] = pkcvt(v0.x, v0.y); p.u[1] = pkcvt(v0.z, v0.w);
      p.u[2] = pkcvt(v1.x, v1.y); p.u[3] = pkcvt(v1.z, v1.w);
      *reinterpret_cast<bf16x8*>(&sA[pb][tid * 8]) = p.v;
    }
    {  // B = att_w: 128x32, 16 f32/thread -> 2 bf16x8
      const float* src = aw + (rowB + (tid >> 1)) * 512 + k0 + (tid & 1) * 16;
      float4 w0 = *reinterpret_cast<const float4*>(src);
      float4 w1 = *reinterpret_cast<const float4*>(src + 4);
      float4 w2 = *reinterpret_cast<const float4*>(src + 8);
      float4 w3 = *reinterpret_cast<const float4*>(src + 12);
      PK p0, p1;
      p0.u[0] = pkcvt(w0.x, w0.y); p0.u[1] = pkcvt(w0.z, w0.w);
      p0.u[2] = pkcvt(w1.x, w1.y); p0.u[3] = pkcvt(w1.z, w1.w);
      p1.u[0] = pkcvt(w2.x, w2.y); p1.u[1] = pkcvt(w2.z, w2.w);
      p1.u[2] = pkcvt(w3.x, w3.y); p1.u[3] = pkcvt(w3.z, w3.w);
      *reinterpret_cast<bf16x8*>(&sB[pb][tid * 16]) = p0.v;
      *reinterpret_cast<bf16x8*>(&sB[pb][tid * 16 + 8]) = p1.v;
    }
  };
  auto comp = [&](int pb) {
    const int kg = (lane >> 4) * 8, rlo = lane & 15;
    bf16x8 af[2], bfv[4];
#pragma unroll
    for (int mm = 0; mm < 2; ++mm)
      af[mm] = *reinterpret_cast<const bf16x8*>(&sA[pb][(32 * wr + 16 * mm + rlo) * 32 + kg]);
#pragma unroll
    for (int nn = 0; nn < 4; ++nn)
      bfv[nn] = *reinterpret_cast<const bf16x8*>(&sB[pb][(64 * wc + 16 * nn + rlo) * 32 + kg]);
#pragma unroll
    for (int mm = 0; mm < 2; ++mm)
#pragma unroll
      for (int nn = 0; nn < 4; ++nn)
        acc[mm][nn] = __builtin_amdgcn_mfma_f32_16x16x32_bf16(af[mm], bfv[nn],
                                                              acc[mm][nn], 0, 0, 0);
  };

  stage(0, 0);
  __syncthreads();
  for (int t = 0; t < 16; t += 2) {
    if (t + 1 < 16) stage(t + 1, 1);
    comp(0);
    __syncthreads();
    if (t + 2 < 16) stage(t + 2, 0);
    comp(1);
    __syncthreads();
  }

#pragma unroll
  for (int mm = 0; mm < 2; ++mm)
#pragma unroll
    for (int nn = 0; nn < 4; ++nn)
#pragma unroll
      for (int r = 0; r < 4; ++r) {
        float v = acc[mm][nn][r];
        int row = (int)rowA + 32 * wr + 16 * mm + (lane >> 4) * 4 + r;
        int col = (int)rowB + 64 * wc + 16 * nn + (lane & 15);
        int s = col >> 9, rem = col & 511;
        int h = rem >> 5, d = rem & 31;
        int b = row >> 10, n = row & 1023;
        if (s == 0) {
          q[((long)(b * nH + h) * nN + n) * nDH + d] = f2bf(v * 0.2550565449825934f);
        } else if (s == 1) {
          kmat[((long)(b * nH + h) * nN + n) * nDH + d] = f2bf(v);
        } else {
          vtt[((long)(b * nH + h) * 32 + (n >> 5)) * 1024 + d * 32 + (n & 31)] = f2bf(v);
        }
      }
}

// ---------------- 2. fused attention: async bias staging, counted vmcnt ------
// grid: x = b*32 + it, y = jc (4-way j split). WG = 16 waves = all 16 heads.
// Bias tiles staged via global_load_lds (zero VALU), swizzled at the GLOBAL
// source (LDS dest must be lane-linear, m104/m173). Raw s_barrier + counted
// vmcnt(1) -> stage(s+1) stays in flight across compute(s) (T4).
// Softmax in log2 domain (coefs/mask/Q pre-scaled by log2e).
__global__ __launch_bounds__(1024) void attn_kernel(
    const unsigned short* __restrict__ qm, const unsigned short* __restrict__ km,
    const unsigned short* __restrict__ vtt,
    const float* __restrict__ pdist, const float* __restrict__ angle,
    const float* __restrict__ adj, const unsigned char* __restrict__ mask,
    const float* __restrict__ gamma_p, const float* __restrict__ gamma_adj,
    const float* __restrict__ w_bias,
    unsigned short* __restrict__ po, float* __restrict__ pm, float* __restrict__ pl) {
  const int b = blockIdx.x >> 5, it = blockIdx.x & 31;
  const int jc = blockIdx.y;
  const int tid = threadIdx.x, wid = tid >> 6, lane = tid & 63;
  const int h = wid;
  const int li = lane & 31, hi = lane >> 5;
  const int ibase = it * 32;

  __shared__ __align__(16) float s_pd[2][1024], s_adj[2][1024];
  __shared__ __align__(16) float s_ang[2][2048];
  __shared__ __align__(16) float s_mk[256];

  const float gp = gamma_p[h] * L2E, ga = gamma_adj[h] * L2E;
  const float wb0 = w_bias[2 * h] * L2E, wb1 = w_bias[2 * h + 1] * L2E;

  const unsigned short* qb = qm + ((long)(b * nH + h) * nN + ibase) * nDH;
  const bf16x8 qf0 = *reinterpret_cast<const bf16x8*>(qb + li * 32 + hi * 8);
  const bf16x8 qf1 = *reinterpret_cast<const bf16x8*>(qb + li * 32 + 16 + hi * 8);

  f32x16 o;
#pragma unroll
  for (int r = 0; r < 16; ++r) o[r] = 0.f;
  float mrun = -INFINITY, lrun = 0.f;

  // one gload16 per thread per tile; 4KB pdist + 4KB adj + 8KB angle = 16KB
  auto stage = [&](int s, int pb) {
    const long jbase = (jc * 8 + s) * 32;
    if (tid < 256) {
      int row = tid >> 3, c = tid & 7;
      int cs = c ^ ((row & 7) ^ (row >> 3));
      gload16(pdist + ((long)b * nN + ibase + row) * nN + jbase + cs * 4,
              (char*)&s_pd[pb][0] + tid * 16);
    } else if (tid < 512) {
      int t2 = tid - 256;
      int row = t2 >> 3, c = t2 & 7;
      int cs = c ^ ((row & 7) ^ (row >> 3));
      gload16(adj + ((long)b * nN + ibase + row) * nN + jbase + cs * 4,
              (char*)&s_adj[pb][0] + t2 * 16);
    } else {
      int t2 = tid - 512;
      int row = t2 >> 4, c = t2 & 15;
      int cs = c ^ ((row & 7) ^ (row >> 3));
      gload16(angle + (((long)b * nN + ibase + row) * nN + jbase) * 2 + cs * 4,
              (char*)&s_ang[pb][0] + t2 * 16);
    }
  };

  auto comp = [&](int s, int pb) {
    const int jt = jc * 8 + s, jbase = jt * 32;
    const unsigned short* kb = km + ((long)(b * nH + h) * nN + jbase) * nDH;
    bf16x8 kf0 = *reinterpret_cast<const bf16x8*>(kb + li * 32 + hi * 8);
    bf16x8 kf1 = *reinterpret_cast<const bf16x8*>(kb + li * 32 + 16 + hi * 8);
    const unsigned short* vb = vtt + ((long)(b * nH + h) * 32 + jt) * 1024;
    bf16x8 vf0 = *reinterpret_cast<const bf16x8*>(vb + li * 32 + hi * 8);
    bf16x8 vf1 = *reinterpret_cast<const bf16x8*>(vb + li * 32 + 16 + hi * 8);

    f32x16 sc;
#pragma unroll
    for (int r = 0; r < 16; ++r) sc[r] = 0.f;
    sc = __builtin_amdgcn_mfma_f32_32x32x16_bf16(kf0, qf0, sc, 0, 0, 0);
    sc = __builtin_amdgcn_mfma_f32_32x32x16_bf16(kf1, qf1, sc, 0, 0, 0);

    const int Sli = (li & 7) ^ (li >> 3);
    float sv[16];
    float tmax = -INFINITY;
#pragma unroll
    for (int g = 0; g < 4; ++g) {
      const int cp = (2 * g + hi) ^ Sli;
      f32x4 pdq = *reinterpret_cast<const f32x4*>(s_pd[pb] + li * 32 + cp * 4);
      f32x4 adq = *reinterpret_cast<const f32x4*>(s_adj[pb] + li * 32 + cp * 4);
      const int ca0 = (4 * g + 2 * hi) ^ Sli, ca1 = (4 * g + 2 * hi + 1) ^ Sli;
      f32x4 av1 = *reinterpret_cast<const f32x4*>(s_ang[pb] + li * 64 + ca0 * 4);
      f32x4 av2 = *reinterpret_cast<const f32x4*>(s_ang[pb] + li * 64 + ca1 * 4);
      const float* mk = s_mk + s * 32 + 8 * g + 4 * hi;
      float a0s[4] = {av1[0], av1[2], av2[0], av2[2]};
      float a1s[4] = {av1[1], av1[3], av2[1], av2[3]};
#pragma unroll
      for (int u = 0; u < 4; ++u) {
        float xv = sc[4 * g + u] - gp * pdq[u] + wb0 * a0s[u] + wb1 * a1s[u]
                   + ga * adq[u] + mk[u];
        sv[4 * g + u] = xv;
        tmax = fmaxf(tmax, xv);
      }
    }
    tmax = fmaxf(tmax, __shfl_xor(tmax, 32));
    if (__any((int)(tmax > mrun + 11.5415603f))) {  // defer-max (8 nats)
      float mnew = fmaxf(mrun, tmax);
      float alpha = exp2f(mrun - mnew);
      lrun *= alpha;
#pragma unroll
      for (int r = 0; r < 16; ++r) o[r] *= bperm((r & 3) + 8 * (r >> 2) + 4 * hi, alpha);
      mrun = mnew;
    }
    float psum = 0.f;
#pragma unroll
    for (int r = 0; r < 16; ++r) { sv[r] = exp2f(sv[r] - mrun); psum += sv[r]; }
    psum += __shfl_xor(psum, 32);
    lrun += psum;

    unsigned ow[8], rw[8];
#pragma unroll
    for (int t = 0; t < 8; ++t) ow[t] = pkcvt(sv[2 * t], sv[2 * t + 1]);
#pragma unroll
    for (int t = 0; t < 8; ++t) rw[t] = __shfl_xor(ow[t], 32);
    union U { unsigned u[4]; bf16x8 v; };
    U u0, u1;
    if (hi == 0) {
      u0.u[0] = ow[0]; u0.u[1] = ow[1]; u0.u[2] = rw[0]; u0.u[3] = rw[1];
      u1.u[0] = ow[4]; u1.u[1] = ow[5]; u1.u[2] = rw[4]; u1.u[3] = rw[5];
    } else {
      u0.u[0] = rw[2]; u0.u[1] = rw[3]; u0.u[2] = ow[2]; u0.u[3] = ow[3];
      u1.u[0] = rw[6]; u1.u[1] = rw[7]; u1.u[2] = ow[6]; u1.u[3] = ow[7];
    }

    o = __builtin_amdgcn_mfma_f32_32x32x16_bf16(u0.v, vf0, o, 0, 0, 0);
    o = __builtin_amdgcn_mfma_f32_32x32x16_bf16(u1.v, vf1, o, 0, 0, 0);
  };

  if (tid < 256)
    s_mk[tid] = mask[b * nN + jc * 256 + tid] ? -1.442695e9f : 0.f;
  stage(0, 0);
  __syncthreads();  // prologue: full drain once (stage(0) + s_mk visible)

  for (int s = 0; s < 8; ++s) {
    const int pb = s & 1;
    if (s < 7) {
      stage(s + 1, pb ^ 1);
      asm volatile("s_waitcnt vmcnt(1)" ::: "memory");  // stage(s) landed
    } else {
      asm volatile("s_waitcnt vmcnt(0)" ::: "memory");
    }
    __builtin_amdgcn_s_barrier();
    comp(s, pb);
    __builtin_amdgcn_s_barrier();  // buf[pb] free for stage(s+2)
  }

  const long task = (((long)(b * nH + h) * 32 + it) * 4 + jc);
  unsigned short* pob = po + task * 1024;
#pragma unroll
  for (int r = 0; r < 16; ++r) {
    const int irow = (r & 3) + 8 * (r >> 2) + 4 * hi;
    pob[irow * 32 + li] = f2bf(o[r]);
  }
  if (hi == 0) { pm[task * 32 + li] = mrun; pl[task * 32 + li] = lrun; }
}

// ---------------- 3. merge 4 j-chunk partials (log2-domain m) ----------------
__global__ __launch_bounds__(256) void merge_kernel(const unsigned short* __restrict__ po,
                                                    const float* __restrict__ pm,
                                                    const float* __restrict__ pl,
                                                    unsigned short* __restrict__ attb) {
  const int x = blockIdx.x;  // (b*16+h)*32+it
  const int t = threadIdx.x;
  const int i = t >> 3, d4 = (t & 7) * 4;
  const long tb = (long)x * 4;
  float m[4], l[4];
#pragma unroll
  for (int c = 0; c < 4; ++c) { m[c] = pm[(tb + c) * 32 + i]; l[c] = pl[(tb + c) * 32 + i]; }
  float M = fmaxf(fmaxf(m[0], m[1]), fmaxf(m[2], m[3]));
  float L = 0.f, w[4];
#pragma unroll
  for (int c = 0; c < 4; ++c) { w[c] = exp2f(m[c] - M); L += w[c] * l[c]; }
  float o0 = 0, o1 = 0, o2 = 0, o3 = 0;
#pragma unroll
  for (int c = 0; c < 4; ++c) {
    ushort4 v = *reinterpret_cast<const ushort4*>(po + (tb + c) * 1024 + i * 32 + d4);
    o0 += w[c] * bf2f(v.x); o1 += w[c] * bf2f(v.y);
    o2 += w[c] * bf2f(v.z); o3 += w[c] * bf2f(v.w);
  }
  const float inv = 1.f / L;
  const int b = x >> 9, hh = (x >> 5) & 15, it = x & 31;
  ushort4 ov;
  ov.x = f2bf(o0 * inv); ov.y = f2bf(o1 * inv);
  ov.z = f2bf(o2 * inv); ov.w = f2bf(o3 * inv);
  *reinterpret_cast<ushort4*>(attb + ((long)b * nN + it * 32 + i) * nD + hh * 32 + d4) = ov;
}

// ---------------- 4. FF GEMM (BN=512 full row) + residual + LayerNorm -------
__global__ __launch_bounds__(512, 2) void ffln_kernel(const unsigned short* __restrict__ attb,
                                                      const unsigned short* __restrict__ fwb,
                                                      const float* __restrict__ x,
                                                      const float* __restrict__ ffb,
                                                      const float* __restrict__ lnw,
                                                      const float* __restrict__ lnb,
                                                      float* __restrict__ out) {
  __shared__ __align__(16) unsigned short sA[2][32 * 32];
  __shared__ __align__(16) unsigned short sB[2][512 * 32];
  __shared__ float rs_[32][4], rs2_[32][4];
  const int tid = threadIdx.x, wid = tid >> 6, lane = tid & 63;
  const int wr = wid >> 2, wc = wid & 3;
  const long rowA = (long)blockIdx.x * 32;

  f32x4 acc[8];
#pragma unroll
  for (int nn = 0; nn < 8; ++nn)
#pragma unroll
    for (int r = 0; r < 4; ++r) acc[nn][r] = 0.f;

  auto stage = [&](int t, int pb) {
    const int k0 = t * 32;
    if (tid < 128)
      gload16(&attb[(rowA + (tid >> 2)) * 512 + k0 + (tid & 3) * 8], &sA[pb][tid * 8]);
#pragma unroll
    for (int c = 0; c < 4; ++c) {
      int off = (tid + 512 * c) * 8;
      int r = off >> 5, s8 = off & 31;
      gload16(&fwb[(long)r * 512 + k0 + s8], &sB[pb][off]);
    }
  };
  auto comp = [&](int pb) {
    const int kg = (lane >> 4) * 8, rlo = lane & 15;
    bf16x8 af = *reinterpret_cast<const bf16x8*>(&sA[pb][(16 * wr + rlo) * 32 + kg]);
#pragma unroll
    for (int nn = 0; nn < 8; ++nn) {
      bf16x8 bfv = *reinterpret_cast<const bf16x8*>(&sB[pb][(128 * wc + 16 * nn + rlo) * 32 + kg]);
      acc[nn] = __builtin_amdgcn_mfma_f32_16x16x32_bf16(af, bfv, acc[nn], 0, 0, 0);
    }
  };

  stage(0, 0);
  __syncthreads();
  for (int t = 0; t < 16; t += 2) {
    if (t + 1 < 16) stage(t + 1, 1);
    comp(0);
    __syncthreads();
    if (t + 2 < 16) stage(t + 2, 0);
    comp(1);
    __syncthreads();
  }

  float colf[8], colw[8], colb[8];
#pragma unroll
  for (int nn = 0; nn < 8; ++nn) {
    int c = 128 * wc + 16 * nn + (lane & 15);
    colf[nn] = ffb[c]; colw[nn] = lnw[c]; colb[nn] = lnb[c];
  }
  float s[4], s2[4];
#pragma unroll
  for (int r = 0; r < 4; ++r) { s[r] = 0.f; s2[r] = 0.f; }
#pragma unroll
  for (int nn = 0; nn < 8; ++nn)
#pragma unroll
    for (int r = 0; r < 4; ++r) {
      long row = rowA + 16 * wr + 4 * (lane >> 4) + r;
      int c = 128 * wc + 16 * nn + (lane & 15);
      float y = acc[nn][r] + colf[nn] + x[row * 512 + c];
      acc[nn][r] = y;
      s[r] += y; s2[r] += y * y;
    }
#pragma unroll
  for (int off = 1; off < 16; off <<= 1)
#pragma unroll
    for (int r = 0; r < 4; ++r) {
      s[r] += __shfl_xor(s[r], off);
      s2[r] += __shfl_xor(s2[r], off);
    }
  if ((lane & 15) == 0) {
#pragma unroll
    for (int r = 0; r < 4; ++r) {
      int rowl = 16 * wr + 4 * (lane >> 4) + r;
      rs_[rowl][wc] = s[r];
      rs2_[rowl][wc] = s2[r];
    }
  }
  __syncthreads();
#pragma unroll
  for (int r = 0; r < 4; ++r) {
    int rowl = 16 * wr + 4 * (lane >> 4) + r;
    float S = rs_[rowl][0] + rs_[rowl][1] + rs_[rowl][2] + rs_[rowl][3];
    float S2 = rs2_[rowl][0] + rs2_[rowl][1] + rs2_[rowl][2] + rs2_[rowl][3];
    float mu = S * (1.f / 512.f);
    float var = S2 * (1.f / 512.f) - mu * mu;
    float rstd = rsqrtf(var + 1e-5f);
    long row = rowA + rowl;
#pragma unroll
    for (int nn = 0; nn < 8; ++nn) {
      int c = 128 * wc + 16 * nn + (lane & 15);
      out[row * 512 + c] = (acc[nn][r] - mu) * rstd * colw[nn] + colb[nn];
    }
  }
}

// ---------------- launch -----------------------------------------------------
extern "C" void kernel_launch(void* const* d_in, const int* in_sizes, int n_in,
                              void* d_out, int out_size, void* d_ws, size_t ws_size,
                              hipStream_t stream) {
  const float* x         = (const float*)d_in[0];
  const float* pdist     = (const float*)d_in[1];
  const float* angle     = (const float*)d_in[2];
  const float* adj       = (const float*)d_in[3];
  const unsigned char* mask = (const unsigned char*)d_in[4];
  const float* gamma_p   = (const float*)d_in[5];
  const float* gamma_adj = (const float*)d_in[6];
  const float* w_bias    = (const float*)d_in[7];
  const float* att_w     = (const float*)d_in[8];
  const float* ff_w      = (const float*)d_in[9];
  const float* ff_b      = (const float*)d_in[10];
  const float* ln_w      = (const float*)d_in[11];
  const float* ln_b      = (const float*)d_in[12];
  float* out = (float*)d_out;

  char* ws = (char*)d_ws;
  unsigned short* qm   = (unsigned short*)(ws);               // 2 MB
  unsigned short* km   = (unsigned short*)(ws + 0x200000);    // 2 MB
  unsigned short* vtt  = (unsigned short*)(ws + 0x400000);    // 2 MB
  unsigned short* po   = (unsigned short*)(ws + 0x600000);    // 8 MB
  float*          pm   = (float*)(ws + 0x1600000);            // 512 KB
  float*          pl   = (float*)(ws + 0x1700000);            // 512 KB
  unsigned short* attb = (unsigned short*)(ws + 0x1800000);   // 2 MB
  unsigned short* fwb  = (unsigned short*)(ws + 0x1A00000);   // 0.5 MB

  hipLaunchKernelGGL(cvt_fw, dim3(256), dim3(256), 0, stream, ff_w, fwb);
  hipLaunchKernelGGL(qkv_gemm, dim3(32, 12), dim3(256), 0, stream,
                     x, att_w, qm, km, vtt);
  hipLaunchKernelGGL(attn_kernel, dim3(64, 4), dim3(1024), 0, stream,
                     qm, km, vtt, pdist, angle, adj, mask,
                     gamma_p, gamma_adj, w_bias, po, pm, pl);
  hipLaunchKernelGGL(merge_kernel, dim3(1024), dim3(256), 0, stream,
                     po, pm, pl, attb);
  hipLaunchKernelGGL(ffln_kernel, dim3(64), dim3(512), 0, stream,
                     attb, fwb, x, ff_b, ln_w, ln_b, out);
}